// Round 8
// baseline (242.664 us; speedup 1.0000x reference)
//
#include <hip/hip_runtime.h>
#include <math.h>

// MultiHeadModulator: single-query complex multi-head attention over L=65536
// past positions, dim=256 (d2=512 real), H=8 heads.
//
// Algebraic reduction (k_proj/v_proj never materialized):
//   scores[l,h] = sum_i z[l,i]*wk[h,i] + ck[h] + relq[idx(l),h]
//   S_un[h,i]   = sum_l exp(scores[l,h]) * z[l,i]     (no max-sub: scores ~N(0,0.5))
//   s[h]        = sum_l exp(scores[l,h])
//   out_real[j] = sum_i Wv[j,i]*S_un[h(j),i]/s[h(j)] + bv[j]
//   out[j']     = sum_j Wo[j',j]*out_real[j] + bo[j']
//
// v9: v8 (=234.6, 5 launches) minus k_matvec512(Wq): qp never materializes.
// Each k_front block computes its own qp slice with the BYTE-IDENTICAL
// wave-dot code from k_matvec512 (same FMA order, same wave_sum), then:
//   blocks 0..15 : wkpart rows [32b,32b+32) (loop byte-identical to v8)
//   blocks 16..23: head h=b-16: qh[64] -> relq[idx*8+h] (129 idx, same serial
//                  k-loop as v8) + ck[h] (same serial loop, 1 thread)
//   blocks 24..39: zero S_un/s slot (b-24)
// Wq is read twice (2MB total, +0.3us); all consumer arithmetic keeps v8's
// exact operation order => absmax 0.0. 4 launches.
// Ledger: launch elim = -3.5us when compute structures preserved (v7,v8);
// front-end ALGORITHM restructure risked +12 once (v5) -- revert if >=238.

static constexpr float SCALE = 0.17677669529663687f; // 1/sqrt(32)
static constexpr int NSLOT = 16;                     // accumulator slots

__device__ __forceinline__ float wave_sum(float v) {
#pragma unroll
  for (int off = 32; off > 0; off >>= 1) v += __shfl_xor(v, off, 64);
  return v;
}

// y[j] = bias[j] + sum_i x[i]*M[j*512+i], 512 rows, one wave per row. grid=128
__global__ __launch_bounds__(256) void k_matvec512(
    const float* __restrict__ M, const float* __restrict__ x,
    const float* __restrict__ bias, float* __restrict__ y) {
  const int wave = threadIdx.x >> 6, lane = threadIdx.x & 63;
  const int j = blockIdx.x * 4 + wave;
  const float* Mr = M + (size_t)j * 512 + lane * 8;
  const float4 m0 = *(const float4*)Mr;
  const float4 m1 = *(const float4*)(Mr + 4);
  const float4 x0 = *(const float4*)(x + lane * 8);
  const float4 x1 = *(const float4*)(x + lane * 8 + 4);
  float acc = m0.x * x0.x + m0.y * x0.y + m0.z * x0.z + m0.w * x0.w +
              m1.x * x1.x + m1.y * x1.y + m1.z * x1.z + m1.w * x1.w;
  acc = wave_sum(acc);
  if (lane == 0) y[j] = acc + bias[j];
}

// Fused front-end: qp slices computed in-block (k_matvec512's exact dot),
// then stage-2 work. grid = 40.
__global__ __launch_bounds__(256) void k_front(
    const float* __restrict__ Wq, const float* __restrict__ z,
    const float* __restrict__ bq, const float* __restrict__ Wk,
    const float* __restrict__ bk, const float* __restrict__ rb,
    float* __restrict__ wkpart, float* __restrict__ ck,
    float* __restrict__ relq, float* __restrict__ S_un,
    float* __restrict__ s) {
  __shared__ float ql[64];
  const int b = blockIdx.x;
  const int wave = threadIdx.x >> 6, lane = threadIdx.x & 63;
  if (b < 16) {
    // qp rows [32b, 32b+32): wave w computes rows 32b+8w..+8 (same dot as
    // k_matvec512: lane*8 float4 pair + wave_sum -> bit-identical)
    const float4 x0 = *(const float4*)(z + lane * 8);
    const float4 x1 = *(const float4*)(z + lane * 8 + 4);
    for (int rr = 0; rr < 8; ++rr) {
      const int j = b * 32 + wave * 8 + rr;
      const float* Mr = Wq + (size_t)j * 512 + lane * 8;
      const float4 m0 = *(const float4*)Mr;
      const float4 m1 = *(const float4*)(Mr + 4);
      float acc = m0.x * x0.x + m0.y * x0.y + m0.z * x0.z + m0.w * x0.w +
                  m1.x * x1.x + m1.y * x1.y + m1.z * x1.z + m1.w * x1.w;
      acc = wave_sum(acc);
      if (lane == 0) ql[wave * 8 + rr] = acc + bq[j];
    }
    __syncthreads();
    // wkpart loop byte-identical to v8 (ql holds qp[b*32..b*32+32))
    for (int i = threadIdx.x; i < 512; i += 256) {
      float acc = 0.f;
#pragma unroll
      for (int k = 0; k < 32; ++k)
        acc += ql[k] * Wk[(size_t)(b * 32 + k) * 512 + i];
      wkpart[b * 512 + i] = acc;
    }
  } else if (b < 24) {
    const int h = b - 16;
    // qh = qp[64h..64h+64): wave w computes 16 rows (same dot pattern)
    const float4 x0 = *(const float4*)(z + lane * 8);
    const float4 x1 = *(const float4*)(z + lane * 8 + 4);
    for (int rr = 0; rr < 16; ++rr) {
      const int j = h * 64 + wave * 16 + rr;
      const float* Mr = Wq + (size_t)j * 512 + lane * 8;
      const float4 m0 = *(const float4*)Mr;
      const float4 m1 = *(const float4*)(Mr + 4);
      float acc = m0.x * x0.x + m0.y * x0.y + m0.z * x0.z + m0.w * x0.w +
                  m1.x * x1.x + m1.y * x1.y + m1.z * x1.z + m1.w * x1.w;
      acc = wave_sum(acc);
      if (lane == 0) ql[wave * 16 + rr] = acc + bq[j];
    }
    __syncthreads();
    // relq for this head: same serial k-loop as v8's k_stage2
    const int t = threadIdx.x;
    if (t < 129) {
      float acc = 0.f;
      for (int k = 0; k < 64; ++k)
        acc += ql[k] * rb[(size_t)t * 512 + h * 64 + k];
      relq[t * 8 + h] = acc * SCALE;
    } else if (t == 255) {
      // ck[h]: same serial loop as v8 (bit-identical order)
      float acc = 0.f;
      for (int k = 0; k < 64; ++k) acc += ql[k] * bk[h * 64 + k];
      ck[h] = acc * SCALE;
    }
  } else {
    const int sl = b - 24;
    for (int t = threadIdx.x; t < 4096; t += 256) S_un[sl * 4096 + t] = 0.f;
    if (threadIdx.x < 8) s[sl * 8 + threadIdx.x] = 0.f;
  }
}

// Fused single pass: scores + exp + weighted z accumulation.
// 128 rows/block (32/wave), grid = L/128 = 512 -> 2 blocks/CU.
// Prologue folds the wk-combine from wkpart (bit-identical arithmetic).
// Tail: 4-wave LDS merge, then atomicAdd into slot (blockIdx & 15) of S_un/s.
__global__ __launch_bounds__(256, 2) void k_attn(
    const float* __restrict__ zp, const float* __restrict__ wkpart,
    const float* __restrict__ ck, const float* __restrict__ relq,
    const int* __restrict__ curr_pos, int L, float* __restrict__ S_un,
    float* __restrict__ s_out) {
  __shared__ float relql[1032];
  __shared__ float Sl[4096];
  __shared__ float sl[4][8];
  const int tid = threadIdx.x;
  const int wave = tid >> 6, lane = tid & 63;
  for (int t = tid; t < 1032; t += 256) relql[t] = relq[t];

  float wkr[8][8];
#pragma unroll
  for (int h = 0; h < 8; ++h) {
    const float4 a0 = *(const float4*)(wkpart + (2 * h) * 512 + lane * 8);
    const float4 a1 = *(const float4*)(wkpart + (2 * h) * 512 + lane * 8 + 4);
    const float4 b0 = *(const float4*)(wkpart + (2 * h + 1) * 512 + lane * 8);
    const float4 b1 = *(const float4*)(wkpart + (2 * h + 1) * 512 + lane * 8 + 4);
    wkr[h][0] = (a0.x + b0.x) * SCALE; wkr[h][1] = (a0.y + b0.y) * SCALE;
    wkr[h][2] = (a0.z + b0.z) * SCALE; wkr[h][3] = (a0.w + b0.w) * SCALE;
    wkr[h][4] = (a1.x + b1.x) * SCALE; wkr[h][5] = (a1.y + b1.y) * SCALE;
    wkr[h][6] = (a1.z + b1.z) * SCALE; wkr[h][7] = (a1.w + b1.w) * SCALE;
  }
  // fold-reduce leaves lane holding head myh = bitrev3(lane&7)
  const int myh = ((lane & 1) << 2) | (lane & 2) | ((lane >> 2) & 1);
  const float ck_my = ck[myh];
  const int cp = curr_pos[0];
  __syncthreads();

  float S[8][8];
#pragma unroll
  for (int h = 0; h < 8; ++h)
#pragma unroll
    for (int k = 0; k < 8; ++k) S[h][k] = 0.f;
  float s_loc = 0.f;

  const int l0 = blockIdx.x * 128 + wave * 32;
  const float* zr = zp + (size_t)l0 * 512 + lane * 8;
  float4 p0 = *(const float4*)zr;
  float4 p1 = *(const float4*)(zr + 4);

#pragma unroll 2
  for (int r = 0; r < 32; ++r) {
    const int l = l0 + r;
    // register prefetch of next row (clamped at the very end)
    const float* zn = (l + 1 < L) ? (zr + 512) : zr;
    const float4 n0 = *(const float4*)zn;
    const float4 n1 = *(const float4*)(zn + 4);
    const float zz[8] = {p0.x, p0.y, p0.z, p0.w, p1.x, p1.y, p1.z, p1.w};
    float acc[8];
#pragma unroll
    for (int h = 0; h < 8; ++h) {
      float a = 0.f;
#pragma unroll
      for (int k = 0; k < 8; ++k) a += zz[k] * wkr[h][k];
      acc[h] = a;
    }
    // fold-reduce: 8 values across 64 lanes in 10 shuffles
    const bool lo1 = (lane & 1) == 0;
    float b0 = (lo1 ? acc[0] : acc[4]) + __shfl_xor(lo1 ? acc[4] : acc[0], 1, 64);
    float b1 = (lo1 ? acc[1] : acc[5]) + __shfl_xor(lo1 ? acc[5] : acc[1], 1, 64);
    float b2 = (lo1 ? acc[2] : acc[6]) + __shfl_xor(lo1 ? acc[6] : acc[2], 1, 64);
    float b3 = (lo1 ? acc[3] : acc[7]) + __shfl_xor(lo1 ? acc[7] : acc[3], 1, 64);
    const bool lo2 = (lane & 2) == 0;
    float c0 = (lo2 ? b0 : b2) + __shfl_xor(lo2 ? b2 : b0, 2, 64);
    float c1 = (lo2 ? b1 : b3) + __shfl_xor(lo2 ? b3 : b1, 2, 64);
    const bool lo3 = (lane & 4) == 0;
    float d = (lo3 ? c0 : c1) + __shfl_xor(lo3 ? c1 : c0, 4, 64);
    d += __shfl_xor(d, 8, 64);
    d += __shfl_xor(d, 16, 64);
    d += __shfl_xor(d, 32, 64);

    int dd = cp - L + l + 64;
    dd = dd < 0 ? 0 : (dd > 128 ? 128 : dd);
    float w = __expf(d + ck_my + relql[dd * 8 + myh]);
    if (l >= L) w = 0.f;
    s_loc += w;
#pragma unroll
    for (int h = 0; h < 8; ++h) {
      const int src = ((h & 1) << 2) | (h & 2) | ((h >> 2) & 1);
      const float wh = __shfl(w, src, 64);
#pragma unroll
      for (int k = 0; k < 8; ++k) S[h][k] += wh * zz[k];
    }
    p0 = n0; p1 = n1; zr += 512;
  }

  if (lane < 8) sl[wave][myh] = s_loc;
  // merge the 4 waves' register tiles into LDS
  for (int wv = 0; wv < 4; ++wv) {
    if (wave == wv) {
#pragma unroll
      for (int h = 0; h < 8; ++h)
#pragma unroll
        for (int k = 0; k < 8; ++k) {
          const int idx = h * 512 + lane * 8 + k;
          if (wv == 0) Sl[idx] = S[h][k];
          else Sl[idx] += S[h][k];
        }
    }
    __syncthreads();
  }
  // slotted global accumulation: chain depth nb/NSLOT instead of nb
  const int slot = blockIdx.x & (NSLOT - 1);
  float* Ss = S_un + slot * 4096;
  for (int t = tid; t < 4096; t += 256) atomicAdd(&Ss[t], Sl[t]);
  if (tid < 8)
    atomicAdd(&s_out[slot * 8 + tid],
              sl[0][tid] + sl[1][tid] + sl[2][tid] + sl[3][tid]);
}

// out_real[j] = bv[j] + (sum_i Wv[j,i]*sum_sl S_un[sl,h(j),i]) / s[h(j)]. grid=128
__global__ __launch_bounds__(256) void k_outreal(
    const float* __restrict__ Wv, const float* __restrict__ S_un,
    const float* __restrict__ s, const float* __restrict__ bv,
    float* __restrict__ out_real) {
  const int wave = threadIdx.x >> 6, lane = threadIdx.x & 63;
  const int j = blockIdx.x * 4 + wave;
  const int h = j >> 6;
  const float* Mr = Wv + (size_t)j * 512 + lane * 8;
  const float4 m0 = *(const float4*)Mr;
  const float4 m1 = *(const float4*)(Mr + 4);
  float x[8] = {0.f, 0.f, 0.f, 0.f, 0.f, 0.f, 0.f, 0.f};
#pragma unroll
  for (int sl = 0; sl < NSLOT; ++sl) {
    const float* xr = S_un + sl * 4096 + h * 512 + lane * 8;
    const float4 a = *(const float4*)xr;
    const float4 b = *(const float4*)(xr + 4);
    x[0] += a.x; x[1] += a.y; x[2] += a.z; x[3] += a.w;
    x[4] += b.x; x[5] += b.y; x[6] += b.z; x[7] += b.w;
  }
  float acc = m0.x * x[0] + m0.y * x[1] + m0.z * x[2] + m0.w * x[3] +
              m1.x * x[4] + m1.y * x[5] + m1.z * x[6] + m1.w * x[7];
  acc = wave_sum(acc);
  if (lane == 0) {
    float sh = 0.f;
#pragma unroll
    for (int sl = 0; sl < NSLOT; ++sl) sh += s[sl * 8 + h];
    out_real[j] = acc / sh + bv[j];
  }
}

extern "C" void kernel_launch(void* const* d_in, const int* in_sizes, int n_in,
                              void* d_out, int out_size, void* d_ws,
                              size_t ws_size, hipStream_t stream) {
  const int* curr_pos = (const int*)d_in[0];
  const float* z_curr = (const float*)d_in[1];
  const float* z_past = (const float*)d_in[2];
  const float* Wq = (const float*)d_in[3];
  const float* bq = (const float*)d_in[4];
  const float* Wk = (const float*)d_in[5];
  const float* bk = (const float*)d_in[6];
  const float* Wv = (const float*)d_in[7];
  const float* bv = (const float*)d_in[8];
  const float* Wo = (const float*)d_in[9];
  const float* bo = (const float*)d_in[10];
  const float* rb = (const float*)d_in[11];
  float* out = (float*)d_out;

  const int L = in_sizes[2] / 512;
  const int nb = (L + 127) / 128;  // attn blocks (128 rows each)

  float* ws = (float*)d_ws;
  size_t o = 0;
  float* wkpart = ws + o;   o += 16 * 512;
  float* ck = ws + o;       o += 16;
  float* relq = ws + o;     o += 1040;
  float* s = ws + o;        o += NSLOT * 8;
  float* S_un = ws + o;     o += NSLOT * 4096;
  float* out_real = ws + o; o += 512;
  (void)ws_size; (void)n_in; (void)out_size;

  k_front<<<40, 256, 0, stream>>>(Wq, z_curr, bq, Wk, bk, rb, wkpart, ck,
                                  relq, S_un, s);
  k_attn<<<nb, 256, 0, stream>>>(z_past, wkpart, ck, relq, curr_pos, L, S_un, s);
  k_outreal<<<128, 256, 0, stream>>>(Wv, S_un, s, bv, out_real);
  k_matvec512<<<128, 256, 0, stream>>>(Wo, out_real, bo, out);
}

// Round 9
// 236.161 us; speedup vs baseline: 1.0275x; 1.0275x over previous
//
#include <hip/hip_runtime.h>
#include <math.h>

// MultiHeadModulator: single-query complex multi-head attention over L=65536
// past positions, dim=256 (d2=512 real), H=8 heads.
//
// Algebraic reduction (k_proj/v_proj never materialized):
//   scores[l,h] = sum_i z[l,i]*wk[h,i] + ck[h] + relq[idx(l),h]
//   S_un[h,i]   = sum_l exp(scores[l,h]) * z[l,i]     (no max-sub: scores ~N(0,0.5))
//   s[h]        = sum_l exp(scores[l,h])
//   out_real[j] = sum_i Wv[j,i]*S_un[h(j),i]/s[h(j)] + bv[j]
//   out[j']     = sum_j Wo[j',j]*out_real[j] + bo[j']
//
// v10 = byte-identical revert to v8 (best known: 234.6us).
// Session ledger (noise ±1us): v1=243.3 -> v7=238.1 (slotted-atomic combine,
// k_comb2 deleted) -> v8=234.6 (k_misc folded into k_stage2 + attn prologue).
// Failed experiments, all reverted:
//   v2/v3 atomic combine depth>32 (+17/+9): device-scope RMW chains serialize.
//   v5 front2 single-stage wk (+12): front-end compute restructure.
//   v9 qp-inline fusion (+8): folding matvecWq's 512 parallel wave-dots into
//     24 consumer blocks serialized 8-16 dots per wave -- fused critical path
//     = sum of parts, not max. Launch-gap saving (~3.5us) < serialization.
// Remaining structure is closed: tail fusion needs grid-wide sync (deadlock
// risk for <=3.5us), k_attn is at its 128MB/6.3TB/s ~ 20.3us stream floor
// (512MiB harness fills evict z_past from L3 each iteration), and ~156us of
// the timed region is harness poison-fill, untouchable from kernel code.

static constexpr float SCALE = 0.17677669529663687f; // 1/sqrt(32)
static constexpr int NSLOT = 16;                     // accumulator slots

__device__ __forceinline__ float wave_sum(float v) {
#pragma unroll
  for (int off = 32; off > 0; off >>= 1) v += __shfl_xor(v, off, 64);
  return v;
}

// y[j] = bias[j] + sum_i x[i]*M[j*512+i], 512 rows, one wave per row. grid=128
__global__ __launch_bounds__(256) void k_matvec512(
    const float* __restrict__ M, const float* __restrict__ x,
    const float* __restrict__ bias, float* __restrict__ y) {
  const int wave = threadIdx.x >> 6, lane = threadIdx.x & 63;
  const int j = blockIdx.x * 4 + wave;
  const float* Mr = M + (size_t)j * 512 + lane * 8;
  const float4 m0 = *(const float4*)Mr;
  const float4 m1 = *(const float4*)(Mr + 4);
  const float4 x0 = *(const float4*)(x + lane * 8);
  const float4 x1 = *(const float4*)(x + lane * 8 + 4);
  float acc = m0.x * x0.x + m0.y * x0.y + m0.z * x0.z + m0.w * x0.w +
              m1.x * x1.x + m1.y * x1.y + m1.z * x1.z + m1.w * x1.w;
  acc = wave_sum(acc);
  if (lane == 0) y[j] = acc + bias[j];
}

// Fused stage 2 (everything that depends only on qp). grid = 39:
//  blocks 0..15 : wkpart[b,i] = sum_{j in [32b,32b+32)} qp[j]*Wk[j,i]
//  blocks 16..21: relq[idx*8+h] = SCALE * sum_k qp[h*64+k]*rb[idx*512+h*64+k]
//  block 22     : ck[h] = SCALE * sum_k qp[h*64+k]*bk[h*64+k]
//  blocks 23..38: zero S_un slot (b-23) and s slot (b-23)
__global__ __launch_bounds__(256) void k_stage2(
    const float* __restrict__ Wk, const float* __restrict__ qp,
    const float* __restrict__ bk, const float* __restrict__ rb,
    float* __restrict__ wkpart, float* __restrict__ ck,
    float* __restrict__ relq, float* __restrict__ S_un,
    float* __restrict__ s) {
  __shared__ float ql[32];
  const int b = blockIdx.x;
  if (b < 16) {
    if (threadIdx.x < 32) ql[threadIdx.x] = qp[b * 32 + threadIdx.x];
    __syncthreads();
    for (int i = threadIdx.x; i < 512; i += 256) {
      float acc = 0.f;
#pragma unroll
      for (int k = 0; k < 32; ++k)
        acc += ql[k] * Wk[(size_t)(b * 32 + k) * 512 + i];
      wkpart[b * 512 + i] = acc;
    }
  } else if (b < 22) {
    const int t = (b - 16) * 256 + threadIdx.x;
    if (t < 129 * 8) {
      const int idx = t >> 3, h = t & 7;
      float acc = 0.f;
      for (int k = 0; k < 64; ++k)
        acc += qp[h * 64 + k] * rb[(size_t)idx * 512 + h * 64 + k];
      relq[t] = acc * SCALE;
    }
  } else if (b == 22) {
    if (threadIdx.x < 8) {
      const int h = threadIdx.x;
      float acc = 0.f;
      for (int k = 0; k < 64; ++k) acc += qp[h * 64 + k] * bk[h * 64 + k];
      ck[h] = acc * SCALE;
    }
  } else {
    const int sl = b - 23;
    for (int t = threadIdx.x; t < 4096; t += 256) S_un[sl * 4096 + t] = 0.f;
    if (threadIdx.x < 8) s[sl * 8 + threadIdx.x] = 0.f;
  }
}

// Fused single pass: scores + exp + weighted z accumulation.
// 128 rows/block (32/wave), grid = L/128 = 512 -> 2 blocks/CU.
// Prologue folds the wk-combine from wkpart (bit-identical arithmetic).
// Tail: 4-wave LDS merge, then atomicAdd into slot (blockIdx & 15) of S_un/s.
__global__ __launch_bounds__(256, 2) void k_attn(
    const float* __restrict__ zp, const float* __restrict__ wkpart,
    const float* __restrict__ ck, const float* __restrict__ relq,
    const int* __restrict__ curr_pos, int L, float* __restrict__ S_un,
    float* __restrict__ s_out) {
  __shared__ float relql[1032];
  __shared__ float Sl[4096];
  __shared__ float sl[4][8];
  const int tid = threadIdx.x;
  const int wave = tid >> 6, lane = tid & 63;
  for (int t = tid; t < 1032; t += 256) relql[t] = relq[t];

  float wkr[8][8];
#pragma unroll
  for (int h = 0; h < 8; ++h) {
    const float4 a0 = *(const float4*)(wkpart + (2 * h) * 512 + lane * 8);
    const float4 a1 = *(const float4*)(wkpart + (2 * h) * 512 + lane * 8 + 4);
    const float4 b0 = *(const float4*)(wkpart + (2 * h + 1) * 512 + lane * 8);
    const float4 b1 = *(const float4*)(wkpart + (2 * h + 1) * 512 + lane * 8 + 4);
    wkr[h][0] = (a0.x + b0.x) * SCALE; wkr[h][1] = (a0.y + b0.y) * SCALE;
    wkr[h][2] = (a0.z + b0.z) * SCALE; wkr[h][3] = (a0.w + b0.w) * SCALE;
    wkr[h][4] = (a1.x + b1.x) * SCALE; wkr[h][5] = (a1.y + b1.y) * SCALE;
    wkr[h][6] = (a1.z + b1.z) * SCALE; wkr[h][7] = (a1.w + b1.w) * SCALE;
  }
  // fold-reduce leaves lane holding head myh = bitrev3(lane&7)
  const int myh = ((lane & 1) << 2) | (lane & 2) | ((lane >> 2) & 1);
  const float ck_my = ck[myh];
  const int cp = curr_pos[0];
  __syncthreads();

  float S[8][8];
#pragma unroll
  for (int h = 0; h < 8; ++h)
#pragma unroll
    for (int k = 0; k < 8; ++k) S[h][k] = 0.f;
  float s_loc = 0.f;

  const int l0 = blockIdx.x * 128 + wave * 32;
  const float* zr = zp + (size_t)l0 * 512 + lane * 8;
  float4 p0 = *(const float4*)zr;
  float4 p1 = *(const float4*)(zr + 4);

#pragma unroll 2
  for (int r = 0; r < 32; ++r) {
    const int l = l0 + r;
    // register prefetch of next row (clamped at the very end)
    const float* zn = (l + 1 < L) ? (zr + 512) : zr;
    const float4 n0 = *(const float4*)zn;
    const float4 n1 = *(const float4*)(zn + 4);
    const float zz[8] = {p0.x, p0.y, p0.z, p0.w, p1.x, p1.y, p1.z, p1.w};
    float acc[8];
#pragma unroll
    for (int h = 0; h < 8; ++h) {
      float a = 0.f;
#pragma unroll
      for (int k = 0; k < 8; ++k) a += zz[k] * wkr[h][k];
      acc[h] = a;
    }
    // fold-reduce: 8 values across 64 lanes in 10 shuffles
    const bool lo1 = (lane & 1) == 0;
    float b0 = (lo1 ? acc[0] : acc[4]) + __shfl_xor(lo1 ? acc[4] : acc[0], 1, 64);
    float b1 = (lo1 ? acc[1] : acc[5]) + __shfl_xor(lo1 ? acc[5] : acc[1], 1, 64);
    float b2 = (lo1 ? acc[2] : acc[6]) + __shfl_xor(lo1 ? acc[6] : acc[2], 1, 64);
    float b3 = (lo1 ? acc[3] : acc[7]) + __shfl_xor(lo1 ? acc[7] : acc[3], 1, 64);
    const bool lo2 = (lane & 2) == 0;
    float c0 = (lo2 ? b0 : b2) + __shfl_xor(lo2 ? b2 : b0, 2, 64);
    float c1 = (lo2 ? b1 : b3) + __shfl_xor(lo2 ? b3 : b1, 2, 64);
    const bool lo3 = (lane & 4) == 0;
    float d = (lo3 ? c0 : c1) + __shfl_xor(lo3 ? c1 : c0, 4, 64);
    d += __shfl_xor(d, 8, 64);
    d += __shfl_xor(d, 16, 64);
    d += __shfl_xor(d, 32, 64);

    int dd = cp - L + l + 64;
    dd = dd < 0 ? 0 : (dd > 128 ? 128 : dd);
    float w = __expf(d + ck_my + relql[dd * 8 + myh]);
    if (l >= L) w = 0.f;
    s_loc += w;
#pragma unroll
    for (int h = 0; h < 8; ++h) {
      const int src = ((h & 1) << 2) | (h & 2) | ((h >> 2) & 1);
      const float wh = __shfl(w, src, 64);
#pragma unroll
      for (int k = 0; k < 8; ++k) S[h][k] += wh * zz[k];
    }
    p0 = n0; p1 = n1; zr += 512;
  }

  if (lane < 8) sl[wave][myh] = s_loc;
  // merge the 4 waves' register tiles into LDS
  for (int wv = 0; wv < 4; ++wv) {
    if (wave == wv) {
#pragma unroll
      for (int h = 0; h < 8; ++h)
#pragma unroll
        for (int k = 0; k < 8; ++k) {
          const int idx = h * 512 + lane * 8 + k;
          if (wv == 0) Sl[idx] = S[h][k];
          else Sl[idx] += S[h][k];
        }
    }
    __syncthreads();
  }
  // slotted global accumulation: chain depth nb/NSLOT instead of nb
  const int slot = blockIdx.x & (NSLOT - 1);
  float* Ss = S_un + slot * 4096;
  for (int t = tid; t < 4096; t += 256) atomicAdd(&Ss[t], Sl[t]);
  if (tid < 8)
    atomicAdd(&s_out[slot * 8 + tid],
              sl[0][tid] + sl[1][tid] + sl[2][tid] + sl[3][tid]);
}

// out_real[j] = bv[j] + (sum_i Wv[j,i]*sum_sl S_un[sl,h(j),i]) / s[h(j)]. grid=128
__global__ __launch_bounds__(256) void k_outreal(
    const float* __restrict__ Wv, const float* __restrict__ S_un,
    const float* __restrict__ s, const float* __restrict__ bv,
    float* __restrict__ out_real) {
  const int wave = threadIdx.x >> 6, lane = threadIdx.x & 63;
  const int j = blockIdx.x * 4 + wave;
  const int h = j >> 6;
  const float* Mr = Wv + (size_t)j * 512 + lane * 8;
  const float4 m0 = *(const float4*)Mr;
  const float4 m1 = *(const float4*)(Mr + 4);
  float x[8] = {0.f, 0.f, 0.f, 0.f, 0.f, 0.f, 0.f, 0.f};
#pragma unroll
  for (int sl = 0; sl < NSLOT; ++sl) {
    const float* xr = S_un + sl * 4096 + h * 512 + lane * 8;
    const float4 a = *(const float4*)xr;
    const float4 b = *(const float4*)(xr + 4);
    x[0] += a.x; x[1] += a.y; x[2] += a.z; x[3] += a.w;
    x[4] += b.x; x[5] += b.y; x[6] += b.z; x[7] += b.w;
  }
  float acc = m0.x * x[0] + m0.y * x[1] + m0.z * x[2] + m0.w * x[3] +
              m1.x * x[4] + m1.y * x[5] + m1.z * x[6] + m1.w * x[7];
  acc = wave_sum(acc);
  if (lane == 0) {
    float sh = 0.f;
#pragma unroll
    for (int sl = 0; sl < NSLOT; ++sl) sh += s[sl * 8 + h];
    out_real[j] = acc / sh + bv[j];
  }
}

extern "C" void kernel_launch(void* const* d_in, const int* in_sizes, int n_in,
                              void* d_out, int out_size, void* d_ws,
                              size_t ws_size, hipStream_t stream) {
  const int* curr_pos = (const int*)d_in[0];
  const float* z_curr = (const float*)d_in[1];
  const float* z_past = (const float*)d_in[2];
  const float* Wq = (const float*)d_in[3];
  const float* bq = (const float*)d_in[4];
  const float* Wk = (const float*)d_in[5];
  const float* bk = (const float*)d_in[6];
  const float* Wv = (const float*)d_in[7];
  const float* bv = (const float*)d_in[8];
  const float* Wo = (const float*)d_in[9];
  const float* bo = (const float*)d_in[10];
  const float* rb = (const float*)d_in[11];
  float* out = (float*)d_out;

  const int L = in_sizes[2] / 512;
  const int nb = (L + 127) / 128;  // attn blocks (128 rows each)

  float* ws = (float*)d_ws;
  size_t o = 0;
  float* qp = ws + o;       o += 512;
  float* wkpart = ws + o;   o += 16 * 512;
  float* ck = ws + o;       o += 16;
  float* relq = ws + o;     o += 1040;
  float* s = ws + o;        o += NSLOT * 8;
  float* S_un = ws + o;     o += NSLOT * 4096;
  float* out_real = ws + o; o += 512;
  (void)ws_size; (void)n_in; (void)out_size;

  k_matvec512<<<128, 256, 0, stream>>>(Wq, z_curr, bq, qp);
  k_stage2<<<39, 256, 0, stream>>>(Wk, qp, bk, rb, wkpart, ck, relq, S_un, s);
  k_attn<<<nb, 256, 0, stream>>>(z_past, wkpart, ck, relq, curr_pos, L, S_un, s);
  k_outreal<<<128, 256, 0, stream>>>(Wv, S_un, s, bv, out_real);
  k_matvec512<<<128, 256, 0, stream>>>(Wo, out_real, bo, out);
}